// Round 1
// 1089.162 us; speedup vs baseline: 1.4316x; 1.4316x over previous
//
#include <hip/hip_runtime.h>
#include <math.h>

#define BB   8
#define CC   256
#define NN   4096
#define DQK  32
#define SCALE 0.17677669529663687f   // 1/sqrt(32)

typedef __bf16 bf16x8 __attribute__((ext_vector_type(8)));
typedef float  f32x4  __attribute__((ext_vector_type(4)));
typedef unsigned short u16x8 __attribute__((ext_vector_type(8)));

__device__ __forceinline__ unsigned short f2bf(float x) {
    unsigned int u = __builtin_bit_cast(unsigned int, x);
    u = (u + 0x7fffu + ((u >> 16) & 1u)) >> 16;   // RNE
    return (unsigned short)u;
}

// ---------------------------------------------------------------------------
// K1: QKV projections. grid (NN/64, BB), block 256 = 64 n-lanes x 4 groups.
// q,k -> bf16 ws laid out [b][n][32] (d contiguous = MFMA fragment layout).
// v   -> bf16 ws [b][c][n] (MFMA A-operand layout for PV).
// ex tile staged in LDS (64 KB): v-loop re-reads become conflict-free ds_read.
// ---------------------------------------------------------------------------
__global__ __launch_bounds__(256) void k_qkv(
    const float* __restrict__ sk, const float* __restrict__ ex,
    const float* __restrict__ Wq, const float* __restrict__ bq,
    const float* __restrict__ Wk, const float* __restrict__ bk,
    const float* __restrict__ Wv, const float* __restrict__ bv,
    unsigned short* __restrict__ qbf, unsigned short* __restrict__ kbf,
    unsigned short* __restrict__ vw)
{
    __shared__ float xs[CC][64];
    const int t  = threadIdx.x;
    const int nl = t & 63;
    const int g  = __builtin_amdgcn_readfirstlane(t >> 6);  // wave-uniform group
    const int b  = blockIdx.y;
    const int nb = blockIdx.x * 64;
    const int n  = nb + nl;

    // stage ex tile [256 c][64 n]
    {
        const float* exb = ex + (size_t)b * CC * NN + nb;
        #pragma unroll 8
        for (int i = 0; i < 64; ++i) {
            const int c = i * 4 + g;
            xs[c][nl] = exb[(size_t)c * NN + nl];
        }
    }
    __syncthreads();

    const float* skb = sk + (size_t)b * CC * NN + n;

    // ---- q: outputs o = g*8 .. g*8+7  (reads sk from global, single use)
    {
        float acc[8];
        #pragma unroll
        for (int j = 0; j < 8; ++j) acc[j] = bq[g * 8 + j];
        #pragma unroll 4
        for (int c = 0; c < CC; ++c) {
            const float x = skb[(size_t)c * NN];
            #pragma unroll
            for (int j = 0; j < 8; ++j) acc[j] += Wq[(g * 8 + j) * CC + c] * x;
        }
        u16x8 r;
        #pragma unroll
        for (int j = 0; j < 8; ++j) r[j] = f2bf(acc[j]);
        *(u16x8*)(qbf + ((size_t)b * NN + n) * DQK + g * 8) = r;
    }
    // ---- k (reads ex from LDS)
    {
        float acc[8];
        #pragma unroll
        for (int j = 0; j < 8; ++j) acc[j] = bk[g * 8 + j];
        #pragma unroll 4
        for (int c = 0; c < CC; ++c) {
            const float x = xs[c][nl];
            #pragma unroll
            for (int j = 0; j < 8; ++j) acc[j] += Wk[(g * 8 + j) * CC + c] * x;
        }
        u16x8 r;
        #pragma unroll
        for (int j = 0; j < 8; ++j) r[j] = f2bf(acc[j]);
        *(u16x8*)(kbf + ((size_t)b * NN + n) * DQK + g * 8) = r;
    }
    // ---- v: outputs o = g*64 + vc*16 + j (256 total across 4 groups)
    #pragma unroll 1
    for (int vc = 0; vc < 4; ++vc) {
        const int o0 = g * 64 + vc * 16;
        float acc[16];
        #pragma unroll
        for (int j = 0; j < 16; ++j) acc[j] = bv[o0 + j];
        #pragma unroll 2
        for (int c = 0; c < CC; ++c) {
            const float x = xs[c][nl];
            #pragma unroll
            for (int j = 0; j < 16; ++j) acc[j] += Wv[(o0 + j) * CC + c] * x;
        }
        #pragma unroll
        for (int j = 0; j < 16; ++j)
            vw[((size_t)b * CC + o0 + j) * NN + n] = f2bf(acc[j]);
    }
}

// ---------------------------------------------------------------------------
// K2 (fused attn+tex): grid 512 blocks (1-D, XCD-swizzled: b = bid&7),
// block 256 = 4 waves. Block owns 64 m-rows; wave w owns m [16w,16w+16) for
// energy/softmax (complete rows -> no cross-wave reduce) and c [64w,64w+64)
// for PV. Energy via mfma_16x16x32_bf16 (K=32 = full d). Pass A: per-lane
// online max/sum + 4x shfl_xor merge. Pass B per 64-n chunk: recompute
// energy (bit-identical), att=exp(e-m)*inv -> HBM fp32 once, bf16 copy ->
// XOR-swizzled LDS (dbuf, 1 barrier/chunk), PV MFMAs consume it. Epilogue
// adds sketches. Eliminates the 512 MB attention HBM re-read entirely.
// ---------------------------------------------------------------------------
__global__ __launch_bounds__(256) void k_fused(
    const unsigned short* __restrict__ qbf,
    const unsigned short* __restrict__ kbf,
    const unsigned short* __restrict__ vw,
    const float* __restrict__ sk,
    float* __restrict__ att, float* __restrict__ outp, float* __restrict__ tex)
{
    __shared__ alignas(16) unsigned short pl[2][64 * 64];   // 16 KB, swizzled
    const int t    = threadIdx.x;
    const int w    = __builtin_amdgcn_readfirstlane(t >> 6);
    const int lane = t & 63;
    const int lc   = lane & 15;
    const int qd   = lane >> 4;
    const int b    = blockIdx.x & 7;          // XCD-swizzle: one batch per XCD
    const int mb   = (blockIdx.x >> 3) * 64;

    // A-frag (Q rows m = mb+16w+lc, k = qd*8..+8), loaded once
    const bf16x8 aq = *(const bf16x8*)(qbf + ((size_t)b * NN + mb + w * 16 + lc) * DQK + qd * 8);
    const unsigned short* kb = kbf + (size_t)b * NN * DQK;
    const f32x4 zero4 = {0.f, 0.f, 0.f, 0.f};

    // ---- pass A: online rowmax/rowsum. Lane covers n ≡ lc (mod 16);
    // reg r ↔ row m_local = 16w + qd*4 + r.
    float rm[4], rs[4];
    #pragma unroll
    for (int r = 0; r < 4; ++r) { rm[r] = -3.0e38f; rs[r] = 0.f; }

    #pragma unroll 2
    for (int n0 = 0; n0 < NN; n0 += 16) {
        const bf16x8 bkf = *(const bf16x8*)(kb + (size_t)(n0 + lc) * DQK + qd * 8);
        const f32x4 e4 = __builtin_amdgcn_mfma_f32_16x16x32_bf16(aq, bkf, zero4, 0, 0, 0);
        #pragma unroll
        for (int r = 0; r < 4; ++r) {
            const float e  = e4[r] * SCALE;
            const float mn = fmaxf(rm[r], e);
            rs[r] = rs[r] * __expf(rm[r] - mn) + __expf(e - mn);
            rm[r] = mn;
        }
    }
    // merge across the 16 col-lanes of each quad group
    #pragma unroll
    for (int off = 1; off <= 8; off <<= 1) {
        #pragma unroll
        for (int r = 0; r < 4; ++r) {
            const float om = __shfl_xor(rm[r], off);
            const float os = __shfl_xor(rs[r], off);
            const float mn = fmaxf(rm[r], om);
            rs[r] = rs[r] * __expf(rm[r] - mn) + os * __expf(om - mn);
            rm[r] = mn;
        }
    }
    float inv[4];
    #pragma unroll
    for (int r = 0; r < 4; ++r) inv[r] = 1.f / rs[r];

    // ---- pass B: recompute energy, emit attention, PV accumulate
    f32x4 acc[4][4];
    #pragma unroll
    for (int i = 0; i < 4; ++i)
        #pragma unroll
        for (int j = 0; j < 4; ++j) acc[i][j] = zero4;

    const unsigned short* vb = vw + (size_t)b * CC * NN;
    float* ab = att + (size_t)b * NN * NN + (size_t)mb * NN;
    const int c0      = w * 64 + lc;
    const int ml_base = w * 16 + qd * 4;

    int cur = 0;
    #pragma unroll 1
    for (int n0 = 0; n0 < NN; n0 += 64) {
        unsigned short* pbase = pl[cur];
        #pragma unroll
        for (int tt = 0; tt < 4; ++tt) {
            const int n = n0 + tt * 16 + lc;
            const bf16x8 bkf = *(const bf16x8*)(kb + (size_t)n * DQK + qd * 8);
            const f32x4 e4 = __builtin_amdgcn_mfma_f32_16x16x32_bf16(aq, bkf, zero4, 0, 0, 0);
            #pragma unroll
            for (int r = 0; r < 4; ++r) {
                const int ml = ml_base + r;
                const float p = __expf(e4[r] * SCALE - rm[r]) * inv[r];
                ab[(size_t)ml * NN + n] = p;                      // final attention, fp32
                const unsigned int byte =
                    (unsigned)(ml * 128 + (tt * 16 + lc) * 2) ^ ((unsigned)(ml & 7) << 4);
                *(unsigned short*)((char*)pbase + byte) = f2bf(p);
            }
        }
        __syncthreads();   // p tile ready; dbuf makes one barrier sufficient
        #pragma unroll
        for (int kk = 0; kk < 64; kk += 32) {
            bf16x8 vf[4], pf[4];
            #pragma unroll
            for (int sc = 0; sc < 4; ++sc)
                vf[sc] = *(const bf16x8*)(vb + (size_t)(c0 + sc * 16) * NN + n0 + kk + qd * 8);
            #pragma unroll
            for (int sm = 0; sm < 4; ++sm) {
                const int m = sm * 16 + lc;
                const unsigned int byte =
                    (unsigned)(m * 128 + kk * 2 + qd * 16) ^ ((unsigned)(m & 7) << 4);
                pf[sm] = *(const bf16x8*)((const char*)pbase + byte);
            }
            #pragma unroll
            for (int sc = 0; sc < 4; ++sc)
                #pragma unroll
                for (int sm = 0; sm < 4; ++sm)
                    acc[sc][sm] = __builtin_amdgcn_mfma_f32_16x16x32_bf16(
                        vf[sc], pf[sm], acc[sc][sm], 0, 0, 0);
        }
        cur ^= 1;
    }

    // epilogue: D[row = c within tile][col = m], row = qd*4 + r
    #pragma unroll
    for (int sc = 0; sc < 4; ++sc) {
        #pragma unroll
        for (int sm = 0; sm < 4; ++sm) {
            #pragma unroll
            for (int r = 0; r < 4; ++r) {
                const int c = w * 64 + sc * 16 + qd * 4 + r;
                const int m = mb + sm * 16 + lc;
                const size_t idx = ((size_t)b * CC + c) * NN + m;
                const float tv = acc[sc][sm][r];
                tex[idx]  = tv;
                outp[idx] = tv + sk[idx];
            }
        }
    }
}

// ---------------------------------------------------------------------------
extern "C" void kernel_launch(void* const* d_in, const int* in_sizes, int n_in,
                              void* d_out, int out_size, void* d_ws, size_t ws_size,
                              hipStream_t stream)
{
    const float* sk = (const float*)d_in[0];
    const float* ex = (const float*)d_in[1];
    const float* Wq = (const float*)d_in[2];
    const float* bq = (const float*)d_in[3];
    const float* Wk = (const float*)d_in[4];
    const float* bk = (const float*)d_in[5];
    const float* Wv = (const float*)d_in[6];
    const float* bv = (const float*)d_in[7];

    float* outp = (float*)d_out;                         // [B,C,N]
    float* tex  = outp + (size_t)BB * CC * NN;           // [B,C,N]
    float* att  = tex  + (size_t)BB * CC * NN;           // [B,N,N]

    unsigned short* qbf = (unsigned short*)d_ws;                 // [B,N,32] bf16, 2 MB
    unsigned short* kbf = qbf + (size_t)BB * NN * DQK;           // [B,N,32] bf16, 2 MB
    unsigned short* vw  = kbf + (size_t)BB * NN * DQK;           // [B,C,N]  bf16, 16 MB

    k_qkv<<<dim3(NN / 64, BB), 256, 0, stream>>>(sk, ex, Wq, bq, Wk, bk, Wv, bv,
                                                 qbf, kbf, vw);
    k_fused<<<dim3((NN / 64) * BB), 256, 0, stream>>>(qbf, kbf, vw, sk,
                                                      att, outp, tex);
}